// Round 12
// baseline (131.726 us; speedup 1.0000x reference)
//
#include <hip/hip_runtime.h>
#include <hip/hip_bf16.h>

namespace {
constexpr int Bb = 8, Hh = 56, Ww = 56, Cc = 192;
constexpr int NQ  = Hh * Ww;        // 3136
constexpr int NKV = 28 * 28;        // 784
constexpr float EPS = 1e-5f;
constexpr float QSCALE = 0.125f * 1.4426950408889634f;  // head scale * log2(e)
}

typedef __attribute__((ext_vector_type(8))) short          bf16x8;
typedef __attribute__((ext_vector_type(4))) float          f32x4;
typedef __attribute__((ext_vector_type(8))) unsigned short u16x8;

__device__ inline unsigned short f2b(float f) {
  __hip_bfloat16 h = __float2bfloat16(f);     // RNE, hardware cvt path
  return __builtin_bit_cast(unsigned short, h);
}

__device__ inline uint2 pack4(float a, float b, float c, float d) {
  uint2 r;
  r.x = (unsigned)f2b(a) | ((unsigned)f2b(b) << 16);
  r.y = (unsigned)f2b(c) | ((unsigned)f2b(d) << 16);
  return r;
}

// ---------------------------------------------------------------------------
// depthwise 3x3 conv (SAME) + batchnorm body (4 channels / thread)
// ---------------------------------------------------------------------------
__device__ inline void dwbn_body(
    int idx, const float* __restrict__ x, const float* __restrict__ w,
    const float* __restrict__ gamma, const float* __restrict__ beta,
    const float* __restrict__ mean, const float* __restrict__ var,
    unsigned short* __restrict__ out, int OH, int OW, int stride, int pad)
{
  int c4 = idx % 48;
  int t = idx / 48;
  int ow = t % OW; t /= OW;
  int oh = t % OH; int b = t / OH;
  const int c = c4 * 4;

  float4 acc = make_float4(0.f, 0.f, 0.f, 0.f);
#pragma unroll
  for (int kh = 0; kh < 3; ++kh) {
    int ih = oh * stride - pad + kh;
    if (ih < 0 || ih >= Hh) continue;
#pragma unroll
    for (int kw = 0; kw < 3; ++kw) {
      int iw = ow * stride - pad + kw;
      if (iw < 0 || iw >= Ww) continue;
      float4 xv = *(const float4*)&x[((size_t)(b * Hh + ih) * Ww + iw) * Cc + c];
      float4 wv = *(const float4*)&w[(kh * 3 + kw) * Cc + c];
      acc.x += xv.x * wv.x; acc.y += xv.y * wv.y;
      acc.z += xv.z * wv.z; acc.w += xv.w * wv.w;
    }
  }
  float4 gm = *(const float4*)&gamma[c];
  float4 bt = *(const float4*)&beta[c];
  float4 mn = *(const float4*)&mean[c];
  float4 vr = *(const float4*)&var[c];
  float r0 = (acc.x - mn.x) * gm.x / sqrtf(vr.x + EPS) + bt.x;
  float r1 = (acc.y - mn.y) * gm.y / sqrtf(vr.y + EPS) + bt.y;
  float r2 = (acc.z - mn.z) * gm.z / sqrtf(vr.z + EPS) + bt.z;
  float r3 = (acc.w - mn.w) * gm.w / sqrtf(vr.w + EPS) + bt.w;
  const size_t row = (size_t)(b * OH + oh) * OW + ow;
  *reinterpret_cast<uint2*>(&out[row * 192 + c]) = pack4(r0, r1, r2, r3);
}

// ---------------------------------------------------------------------------
// fused stage 1: dwbn(q) [blocks 0..4703] + dwbn(kv) [4704..5879]
//              + weight transpose->bf16 [5880..6455]
// ---------------------------------------------------------------------------
__global__ __launch_bounds__(256) void stage1_kernel(
    const float* __restrict__ x,
    const float* __restrict__ dw_q, const float* __restrict__ q_gamma,
    const float* __restrict__ q_beta, const float* __restrict__ q_mean,
    const float* __restrict__ q_var,
    const float* __restrict__ dw_kv, const float* __restrict__ kv_gamma,
    const float* __restrict__ kv_beta, const float* __restrict__ kv_mean,
    const float* __restrict__ kv_var,
    const float* __restrict__ pwq, const float* __restrict__ pwkv,
    const float* __restrict__ outw,
    unsigned short* __restrict__ dwq, unsigned short* __restrict__ dwkv,
    unsigned short* __restrict__ wq, unsigned short* __restrict__ wkv,
    unsigned short* __restrict__ wo)
{
  const int blk = blockIdx.x;
  if (blk < 4704) {
    dwbn_body(blk * 256 + threadIdx.x, x, dw_q, q_gamma, q_beta, q_mean, q_var,
              dwq, 56, 56, 1, 1);
  } else if (blk < 5880) {
    dwbn_body((blk - 4704) * 256 + threadIdx.x, x, dw_kv, kv_gamma, kv_beta,
              kv_mean, kv_var, dwkv, 28, 28, 2, 0);
  } else {
    int i = (blk - 5880) * 256 + threadIdx.x;
    if (i < 36864) {                       // wq [192][192]
      int n = i / 192, k = i - n * 192;
      wq[i] = f2b(pwq[k * 192 + n]);
    } else if (i < 110592) {               // wkv [384][192]
      int j = i - 36864;
      int n = j / 192, k = j - n * 192;
      wkv[j] = f2b(pwkv[k * 384 + n]);
    } else {                               // wo [192][192]
      int j = i - 110592;
      int n = j / 192, k = j - n * 192;
      wo[j] = f2b(outw[k * 192 + n]);
    }
  }
}

// ---------------------------------------------------------------------------
// bf16 MFMA GEMM for q & kv pointwise (round-6 proven 128x64 tiling):
//  blocks [0,588): dwq[25088,192] x Wq^T -> Qbuf (per-head, scaled by QSCALE)
//  blocks [588,882): dwkv[6272,192] x Wkv^T -> Kbuf (per-head) + Vtbuf
// ---------------------------------------------------------------------------
__global__ __launch_bounds__(256) void gemm_qkv_kernel(
    const unsigned short* __restrict__ dwq, const unsigned short* __restrict__ dwkv,
    const unsigned short* __restrict__ Wq, const unsigned short* __restrict__ Wkv,
    unsigned short* __restrict__ Qbuf, unsigned short* __restrict__ Kbuf,
    unsigned short* __restrict__ Vtbuf)
{
  __shared__ unsigned short As[128][72];
  __shared__ unsigned short Bs[64][72];

  const int blk = blockIdx.x;
  const bool isQ = blk < 588;
  const int lb = isQ ? blk : blk - 588;
  const unsigned short* __restrict__ A  = isQ ? dwq : dwkv;
  const unsigned short* __restrict__ Bt = isQ ? Wq : Wkv;
  const int nbl = isQ ? 3 : 6;
  const int NR  = isQ ? 3136 : 784;

  const int bm = lb / nbl, bn = lb % nbl;
  const int row0 = bm << 7, col0 = bn << 6;
  const int tid = threadIdx.x;
  const int lane = tid & 63, w = tid >> 6;
  const int lr = lane & 15, lg = lane >> 4;
  const int wm = w >> 1, wn = w & 1;

  f32x4 acc[4][2];
#pragma unroll
  for (int mr = 0; mr < 4; ++mr)
#pragma unroll
    for (int nr = 0; nr < 2; ++nr) acc[mr][nr] = (f32x4){0.f, 0.f, 0.f, 0.f};

  for (int k0 = 0; k0 < 192; k0 += 64) {
    {
      const int r = tid >> 1, c0 = (tid & 1) * 32;
      const unsigned short* src = A + (size_t)(row0 + r) * 192 + k0 + c0;
#pragma unroll
      for (int u = 0; u < 4; ++u)
        *(u16x8*)&As[r][c0 + u * 8] = *(const u16x8*)&src[u * 8];
    }
    {
      const int n = tid >> 2, c0 = (tid & 3) * 16;
      const unsigned short* src = Bt + (size_t)(col0 + n) * 192 + k0 + c0;
#pragma unroll
      for (int u = 0; u < 2; ++u)
        *(u16x8*)&Bs[n][c0 + u * 8] = *(const u16x8*)&src[u * 8];
    }
    __syncthreads();
#pragma unroll
    for (int ks = 0; ks < 2; ++ks) {
      bf16x8 a[4], b[2];
#pragma unroll
      for (int mr = 0; mr < 4; ++mr)
        a[mr] = *(const bf16x8*)&As[wm * 64 + mr * 16 + lr][ks * 32 + lg * 8];
#pragma unroll
      for (int nr = 0; nr < 2; ++nr)
        b[nr] = *(const bf16x8*)&Bs[wn * 32 + nr * 16 + lr][ks * 32 + lg * 8];
#pragma unroll
      for (int mr = 0; mr < 4; ++mr)
#pragma unroll
        for (int nr = 0; nr < 2; ++nr)
          acc[mr][nr] = __builtin_amdgcn_mfma_f32_16x16x32_bf16(a[mr], b[nr], acc[mr][nr], 0, 0, 0);
    }
    __syncthreads();
  }

#pragma unroll
  for (int mr = 0; mr < 4; ++mr) {
#pragma unroll
    for (int nr = 0; nr < 2; ++nr) {
      const int c = col0 + wn * 32 + nr * 16 + lr;
      const int rbase = row0 + wm * 64 + mr * 16 + lg * 4;
      if (isQ) {
        const int h = c >> 6, d = c & 63;
        const int b = rbase / 3136;
        const int n0 = rbase - b * 3136;
#pragma unroll
        for (int j = 0; j < 4; ++j)
          Qbuf[(((size_t)b * 3 + h) * 3136 + n0 + j) * 64 + d] = f2b(acc[mr][nr][j] * QSCALE);
      } else if (c < 192) {
        const int h = c >> 6, d = c & 63;
        const int b = rbase / 784;
        const int n0 = rbase - b * 784;
#pragma unroll
        for (int j = 0; j < 4; ++j)
          Kbuf[(((size_t)b * 3 + h) * 784 + n0 + j) * 64 + d] = f2b(acc[mr][nr][j]);
      } else {
        const int h = (c - 192) >> 6, d = (c - 192) & 63;
        const int b = rbase / 784;
        const int n0 = rbase - b * 784;
        uint2 v = pack4(acc[mr][nr][0], acc[mr][nr][1], acc[mr][nr][2], acc[mr][nr][3]);
        *reinterpret_cast<uint2*>(&Vtbuf[(((size_t)b * 3 + h) * 64 + d) * 784 + n0]) = v;
      }
    }
  }
}

// ---------------------------------------------------------------------------
// output projection (round-6 proven): O[25088,192](bf16) x Wo^T + bias -> fp32
// ---------------------------------------------------------------------------
__global__ __launch_bounds__(256) void gemm_out_kernel(
    const unsigned short* __restrict__ A, const unsigned short* __restrict__ Bt,
    const float* __restrict__ bias, float* __restrict__ O32)
{
  __shared__ unsigned short As[128][72];
  __shared__ unsigned short Bs[64][72];

  const int bm = blockIdx.x / 3, bn = blockIdx.x % 3;
  const int row0 = bm << 7, col0 = bn << 6;
  const int tid = threadIdx.x;
  const int lane = tid & 63, w = tid >> 6;
  const int lr = lane & 15, lg = lane >> 4;
  const int wm = w >> 1, wn = w & 1;

  f32x4 acc[4][2];
#pragma unroll
  for (int mr = 0; mr < 4; ++mr)
#pragma unroll
    for (int nr = 0; nr < 2; ++nr) acc[mr][nr] = (f32x4){0.f, 0.f, 0.f, 0.f};

  for (int k0 = 0; k0 < 192; k0 += 64) {
    {
      const int r = tid >> 1, c0 = (tid & 1) * 32;
      const unsigned short* src = A + (size_t)(row0 + r) * 192 + k0 + c0;
#pragma unroll
      for (int u = 0; u < 4; ++u)
        *(u16x8*)&As[r][c0 + u * 8] = *(const u16x8*)&src[u * 8];
    }
    {
      const int n = tid >> 2, c0 = (tid & 3) * 16;
      const unsigned short* src = Bt + (size_t)(col0 + n) * 192 + k0 + c0;
#pragma unroll
      for (int u = 0; u < 2; ++u)
        *(u16x8*)&Bs[n][c0 + u * 8] = *(const u16x8*)&src[u * 8];
    }
    __syncthreads();
#pragma unroll
    for (int ks = 0; ks < 2; ++ks) {
      bf16x8 a[4], b[2];
#pragma unroll
      for (int mr = 0; mr < 4; ++mr)
        a[mr] = *(const bf16x8*)&As[wm * 64 + mr * 16 + lr][ks * 32 + lg * 8];
#pragma unroll
      for (int nr = 0; nr < 2; ++nr)
        b[nr] = *(const bf16x8*)&Bs[wn * 32 + nr * 16 + lr][ks * 32 + lg * 8];
#pragma unroll
      for (int mr = 0; mr < 4; ++mr)
#pragma unroll
        for (int nr = 0; nr < 2; ++nr)
          acc[mr][nr] = __builtin_amdgcn_mfma_f32_16x16x32_bf16(a[mr], b[nr], acc[mr][nr], 0, 0, 0);
    }
    __syncthreads();
  }

#pragma unroll
  for (int mr = 0; mr < 4; ++mr) {
#pragma unroll
    for (int nr = 0; nr < 2; ++nr) {
      const int c = col0 + wn * 32 + nr * 16 + lr;
      const int rbase = row0 + wm * 64 + mr * 16 + lg * 4;
      const float bb = bias[c];
#pragma unroll
      for (int j = 0; j < 4; ++j)
        O32[(size_t)(rbase + j) * 192 + c] = acc[mr][nr][j] + bb;
    }
  }
}

// ---------------------------------------------------------------------------
// MFMA flash attention, barrier-free: K/V fragments loaded DIRECTLY from
// global (L1/L2-resident via XCD swizzle; K+V per bh = 200KB << 4MB L2).
// No K/V LDS staging, no __syncthreads — all 4 waves fully independent.
// P keeps its wave-private LDS round-trip (no barrier needed).
// Same K/V bits, same per-row op order as round 6 -> bitwise-identical.
// ---------------------------------------------------------------------------
__global__ __launch_bounds__(256) void attn_mfma_kernel(
    const unsigned short* __restrict__ Qb, const unsigned short* __restrict__ Kb,
    const unsigned short* __restrict__ Vtb, unsigned short* __restrict__ Ob)
{
  __shared__ unsigned short Ps[64][72];    // P tile (wave-private rows), 72-pad
  __shared__ float ls[4][16];

  const int raw = blockIdx.x;
  const int blk = (raw & 7) * 147 + (raw >> 3);  // XCD-chunked swizzle (8*147=1176)
  const int qt = blk % 49;
  const int bh = blk / 49;                 // b*3 + h
  const int n0 = qt * 64;
  const int tid = threadIdx.x;
  const int lane = tid & 63;
  const int w = tid >> 6;
  const int lr = lane & 15, lg = lane >> 4;
  const int prow = w * 16 + lr;            // wave-private P row

  // Q fragment straight from global (L2-resident)
  const unsigned short* qrow = Qb + ((size_t)bh * NQ + n0 + w * 16 + lr) * 64;
  const bf16x8 aq0 = *(const bf16x8*)&qrow[lg * 8];
  const bf16x8 aq1 = *(const bf16x8*)&qrow[32 + lg * 8];

  // per-lane fragment base pointers
  //  K frag (nb): row nb*16+lr, cols lg*8 / 32+lg*8 of tile kt
  const unsigned short* kbase = Kb + (size_t)bh * NKV * 64 + (size_t)lr * 64 + lg * 8;
  //  V frag (db): row bh*64 + db*16 + lr, cols kt*64 + lg*8 / +32
  const unsigned short* vbase = Vtb + ((size_t)bh * 64 + lr) * NKV + lg * 8;

  f32x4 oacc[4];
#pragma unroll
  for (int db = 0; db < 4; ++db) oacc[db] = (f32x4){0.f, 0.f, 0.f, 0.f};
  float lsum = 0.f;

  for (int kt = 0; kt < 12; ++kt) {
    const unsigned short* kp = kbase + (size_t)kt * 64 * 64;
    const unsigned short* vp = vbase + kt * 64;

    // S^T = K.Q^T : st[nb][r] = S[q=lr][kv = kt*64 + nb*16 + lg*4 + r]
    f32x4 st[4];
    __builtin_amdgcn_s_setprio(1);
#pragma unroll
    for (int nb = 0; nb < 4; ++nb) {
      const bf16x8 bk0 = *(const bf16x8*)(kp + (size_t)nb * 16 * 64);
      const bf16x8 bk1 = *(const bf16x8*)(kp + (size_t)nb * 16 * 64 + 32);
      f32x4 a = (f32x4){0.f, 0.f, 0.f, 0.f};
      a = __builtin_amdgcn_mfma_f32_16x16x32_bf16(bk0, aq0, a, 0, 0, 0);
      a = __builtin_amdgcn_mfma_f32_16x16x32_bf16(bk1, aq1, a, 0, 0, 0);
      st[nb] = a;
    }
    __builtin_amdgcn_s_setprio(0);

    // p = exp2(s') (log2e pre-folded into Q), partial denom, pack -> Ps
#pragma unroll
    for (int nb = 0; nb < 4; ++nb) {
      float p[4];
#pragma unroll
      for (int r = 0; r < 4; ++r) p[r] = exp2f(st[nb][r]);
      lsum += (p[0] + p[1]) + (p[2] + p[3]);
      uint2 u = pack4(p[0], p[1], p[2], p[3]);
      *reinterpret_cast<uint2*>(&Ps[prow][nb * 16 + lg * 4]) = u;
    }

    // O += P V  (Ps rows wave-private: same-wave DS in-order, no barrier)
    const bf16x8 pa0 = *(const bf16x8*)&Ps[prow][lg * 8];
    const bf16x8 pa1 = *(const bf16x8*)&Ps[prow][32 + lg * 8];
    __builtin_amdgcn_s_setprio(1);
#pragma unroll
    for (int db = 0; db < 4; ++db) {
      const bf16x8 vb0 = *(const bf16x8*)(vp + (size_t)db * 16 * NKV);
      const bf16x8 vb1 = *(const bf16x8*)(vp + (size_t)db * 16 * NKV + 32);
      oacc[db] = __builtin_amdgcn_mfma_f32_16x16x32_bf16(pa0, vb0, oacc[db], 0, 0, 0);
      oacc[db] = __builtin_amdgcn_mfma_f32_16x16x32_bf16(pa1, vb1, oacc[db], 0, 0, 0);
    }
    __builtin_amdgcn_s_setprio(0);
  }

  // tail tile (kt=12): kv 768..783 valid -> only nb=0; zero nb=1 slot of Ps
  {
    const unsigned short* kp = kbase + (size_t)12 * 64 * 64;   // rows 768+lr
    const bf16x8 bk0 = *(const bf16x8*)(kp);
    const bf16x8 bk1 = *(const bf16x8*)(kp + 32);
    f32x4 a = (f32x4){0.f, 0.f, 0.f, 0.f};
    a = __builtin_amdgcn_mfma_f32_16x16x32_bf16(bk0, aq0, a, 0, 0, 0);
    a = __builtin_amdgcn_mfma_f32_16x16x32_bf16(bk1, aq1, a, 0, 0, 0);
    float p[4];
#pragma unroll
    for (int r = 0; r < 4; ++r) p[r] = exp2f(a[r]);   // lg*4+r < 16: all valid
    lsum += (p[0] + p[1]) + (p[2] + p[3]);
    *reinterpret_cast<uint2*>(&Ps[prow][lg * 4]) = pack4(p[0], p[1], p[2], p[3]);
    uint2 z; z.x = 0u; z.y = 0u;
    *reinterpret_cast<uint2*>(&Ps[prow][16 + lg * 4]) = z;
    const bf16x8 pa0 = *(const bf16x8*)&Ps[prow][lg * 8];      // k = lg*8..+8
    // V cols 768 + lg*8 .. +8: OOB for lg>=2 -> clamp (those k have P=0)
    const int vc = (768 + lg * 8 <= NKV - 8) ? 768 + lg * 8 : NKV - 8;
    const unsigned short* vp = Vtb + ((size_t)bh * 64 + lr) * NKV + vc;
#pragma unroll
    for (int db = 0; db < 4; ++db) {
      const bf16x8 vb0 = *(const bf16x8*)(vp + (size_t)db * 16 * NKV);
      oacc[db] = __builtin_amdgcn_mfma_f32_16x16x32_bf16(pa0, vb0, oacc[db], 0, 0, 0);
    }
  }

  // final denominator: lanes {lr, lr+16, lr+32, lr+48} hold partials for q=lr
  float l = lsum;
  l += __shfl_xor(l, 16);
  l += __shfl_xor(l, 32);
  if (lg == 0) ls[w][lr] = l;
  const float4 lv = *(const float4*)&ls[w][lg * 4];   // wave-private, in-order

  const int b = bh / 3, h = bh - b * 3;
  float linv[4];
#pragma unroll
  for (int j = 0; j < 4; ++j) linv[j] = 1.f / ((&lv.x)[j]);
#pragma unroll
  for (int j = 0; j < 4; ++j) {
    const int qg = n0 + w * 16 + lg * 4 + j;
    unsigned short* orow = Ob + ((size_t)b * NQ + qg) * 192 + h * 64 + lr;
#pragma unroll
    for (int db = 0; db < 4; ++db) orow[db * 16] = f2b(oacc[db][j] * linv[j]);
  }
}

// ---------------------------------------------------------------------------
extern "C" void kernel_launch(void* const* d_in, const int* in_sizes, int n_in,
                              void* d_out, int out_size, void* d_ws, size_t ws_size,
                              hipStream_t stream)
{
  const float* x        = (const float*)d_in[0];
  const float* dw_q     = (const float*)d_in[1];
  const float* q_gamma  = (const float*)d_in[2];
  const float* q_beta   = (const float*)d_in[3];
  const float* q_mean   = (const float*)d_in[4];
  const float* q_var    = (const float*)d_in[5];
  const float* pw_q     = (const float*)d_in[6];
  const float* dw_kv    = (const float*)d_in[7];
  const float* kv_gamma = (const float*)d_in[8];
  const float* kv_beta  = (const float*)d_in[9];
  const float* kv_mean  = (const float*)d_in[10];
  const float* kv_var   = (const float*)d_in[11];
  const float* pw_kv    = (const float*)d_in[12];
  const float* out_w    = (const float*)d_in[13];
  const float* out_b    = (const float*)d_in[14];
  float* out = (float*)d_out;

  unsigned short* dwq   = (unsigned short*)d_ws;          // 25088*192 (later O)
  unsigned short* dwkv  = dwq   + (size_t)25088 * 192;    // 6272*192
  unsigned short* Qbuf  = dwkv  + (size_t)6272 * 192;     // 24*3136*64
  unsigned short* Kbuf  = Qbuf  + (size_t)24 * 3136 * 64; // 24*784*64
  unsigned short* Vtbuf = Kbuf  + (size_t)24 * 784 * 64;  // 24*64*784
  unsigned short* Wq    = Vtbuf + (size_t)24 * 784 * 64;  // 192*192
  unsigned short* Wkv   = Wq + 36864;                     // 384*192
  unsigned short* Wo    = Wkv + 73728;                    // 192*192

  // 1. fused: dwbn(q) + dwbn(kv) + weight prep
  stage1_kernel<<<6456, 256, 0, stream>>>(
      x, dw_q, q_gamma, q_beta, q_mean, q_var,
      dw_kv, kv_gamma, kv_beta, kv_mean, kv_var,
      pw_q, pw_kv, out_w, dwq, dwkv, Wq, Wkv, Wo);
  // 2. pointwise GEMMs (round-6 tiling): q -> Qbuf, kv -> Kbuf + Vtbuf
  gemm_qkv_kernel<<<882, 256, 0, stream>>>(dwq, dwkv, Wq, Wkv, Qbuf, Kbuf, Vtbuf);
  // 3. MFMA attention (barrier-free, direct K/V from L2) -> dwq
  attn_mfma_kernel<<<8 * 3 * 49, 256, 0, stream>>>(Qbuf, Kbuf, Vtbuf, dwq);
  // 4. output projection + bias -> d_out (fp32)
  gemm_out_kernel<<<588, 256, 0, stream>>>(dwq, Wo, out_b, out);
}

// Round 13
// 93.005 us; speedup vs baseline: 1.4163x; 1.4163x over previous
//
#include <hip/hip_runtime.h>
#include <hip/hip_bf16.h>

namespace {
constexpr int Bb = 8, Hh = 56, Ww = 56, Cc = 192;
constexpr int NQ  = Hh * Ww;        // 3136
constexpr int NKV = 28 * 28;        // 784
constexpr float EPS = 1e-5f;
constexpr float QSCALE = 0.125f * 1.4426950408889634f;  // head scale * log2(e)
}

typedef __attribute__((ext_vector_type(8))) short          bf16x8;
typedef __attribute__((ext_vector_type(4))) short          bf16x4;
typedef __attribute__((ext_vector_type(4))) float          f32x4;
typedef __attribute__((ext_vector_type(8))) unsigned short u16x8;

__device__ inline unsigned short f2b(float f) {
  __hip_bfloat16 h = __float2bfloat16(f);     // RNE, hardware cvt path
  return __builtin_bit_cast(unsigned short, h);
}

__device__ inline uint2 pack4(float a, float b, float c, float d) {
  uint2 r;
  r.x = (unsigned)f2b(a) | ((unsigned)f2b(b) << 16);
  r.y = (unsigned)f2b(c) | ((unsigned)f2b(d) << 16);
  return r;
}

// ---------------------------------------------------------------------------
// depthwise 3x3 conv (SAME) + batchnorm body (4 channels / thread)
// ---------------------------------------------------------------------------
__device__ inline void dwbn_body(
    int idx, const float* __restrict__ x, const float* __restrict__ w,
    const float* __restrict__ gamma, const float* __restrict__ beta,
    const float* __restrict__ mean, const float* __restrict__ var,
    unsigned short* __restrict__ out, int OH, int OW, int stride, int pad)
{
  int c4 = idx % 48;
  int t = idx / 48;
  int ow = t % OW; t /= OW;
  int oh = t % OH; int b = t / OH;
  const int c = c4 * 4;

  float4 acc = make_float4(0.f, 0.f, 0.f, 0.f);
#pragma unroll
  for (int kh = 0; kh < 3; ++kh) {
    int ih = oh * stride - pad + kh;
    if (ih < 0 || ih >= Hh) continue;
#pragma unroll
    for (int kw = 0; kw < 3; ++kw) {
      int iw = ow * stride - pad + kw;
      if (iw < 0 || iw >= Ww) continue;
      float4 xv = *(const float4*)&x[((size_t)(b * Hh + ih) * Ww + iw) * Cc + c];
      float4 wv = *(const float4*)&w[(kh * 3 + kw) * Cc + c];
      acc.x += xv.x * wv.x; acc.y += xv.y * wv.y;
      acc.z += xv.z * wv.z; acc.w += xv.w * wv.w;
    }
  }
  float4 gm = *(const float4*)&gamma[c];
  float4 bt = *(const float4*)&beta[c];
  float4 mn = *(const float4*)&mean[c];
  float4 vr = *(const float4*)&var[c];
  float r0 = (acc.x - mn.x) * gm.x / sqrtf(vr.x + EPS) + bt.x;
  float r1 = (acc.y - mn.y) * gm.y / sqrtf(vr.y + EPS) + bt.y;
  float r2 = (acc.z - mn.z) * gm.z / sqrtf(vr.z + EPS) + bt.z;
  float r3 = (acc.w - mn.w) * gm.w / sqrtf(vr.w + EPS) + bt.w;
  const size_t row = (size_t)(b * OH + oh) * OW + ow;
  *reinterpret_cast<uint2*>(&out[row * 192 + c]) = pack4(r0, r1, r2, r3);
}

// ---------------------------------------------------------------------------
// fused stage 1: dwbn(q) [blocks 0..4703] + dwbn(kv) [4704..5879]
//              + weight transpose->bf16 [5880..6455]
// ---------------------------------------------------------------------------
__global__ __launch_bounds__(256) void stage1_kernel(
    const float* __restrict__ x,
    const float* __restrict__ dw_q, const float* __restrict__ q_gamma,
    const float* __restrict__ q_beta, const float* __restrict__ q_mean,
    const float* __restrict__ q_var,
    const float* __restrict__ dw_kv, const float* __restrict__ kv_gamma,
    const float* __restrict__ kv_beta, const float* __restrict__ kv_mean,
    const float* __restrict__ kv_var,
    const float* __restrict__ pwq, const float* __restrict__ pwkv,
    const float* __restrict__ outw,
    unsigned short* __restrict__ dwq, unsigned short* __restrict__ dwkv,
    unsigned short* __restrict__ wq, unsigned short* __restrict__ wkv,
    unsigned short* __restrict__ wo)
{
  const int blk = blockIdx.x;
  if (blk < 4704) {
    dwbn_body(blk * 256 + threadIdx.x, x, dw_q, q_gamma, q_beta, q_mean, q_var,
              dwq, 56, 56, 1, 1);
  } else if (blk < 5880) {
    dwbn_body((blk - 4704) * 256 + threadIdx.x, x, dw_kv, kv_gamma, kv_beta,
              kv_mean, kv_var, dwkv, 28, 28, 2, 0);
  } else {
    int i = (blk - 5880) * 256 + threadIdx.x;
    if (i < 36864) {                       // wq [192][192]
      int n = i / 192, k = i - n * 192;
      wq[i] = f2b(pwq[k * 192 + n]);
    } else if (i < 110592) {               // wkv [384][192]
      int j = i - 36864;
      int n = j / 192, k = j - n * 192;
      wkv[j] = f2b(pwkv[k * 384 + n]);
    } else {                               // wo [192][192]
      int j = i - 110592;
      int n = j / 192, k = j - n * 192;
      wo[j] = f2b(outw[k * 192 + n]);
    }
  }
}

// ---------------------------------------------------------------------------
// bf16 MFMA GEMM for q & kv pointwise (round-6 proven 128x64 tiling):
//  blocks [0,588): dwq[25088,192] x Wq^T -> Qbuf (per-head, scaled by QSCALE)
//  blocks [588,882): dwkv[6272,192] x Wkv^T -> Kbuf (per-head) + Vtbuf
// ---------------------------------------------------------------------------
__global__ __launch_bounds__(256) void gemm_qkv_kernel(
    const unsigned short* __restrict__ dwq, const unsigned short* __restrict__ dwkv,
    const unsigned short* __restrict__ Wq, const unsigned short* __restrict__ Wkv,
    unsigned short* __restrict__ Qbuf, unsigned short* __restrict__ Kbuf,
    unsigned short* __restrict__ Vtbuf)
{
  __shared__ unsigned short As[128][72];
  __shared__ unsigned short Bs[64][72];

  const int blk = blockIdx.x;
  const bool isQ = blk < 588;
  const int lb = isQ ? blk : blk - 588;
  const unsigned short* __restrict__ A  = isQ ? dwq : dwkv;
  const unsigned short* __restrict__ Bt = isQ ? Wq : Wkv;
  const int nbl = isQ ? 3 : 6;
  const int NR  = isQ ? 3136 : 784;

  const int bm = lb / nbl, bn = lb % nbl;
  const int row0 = bm << 7, col0 = bn << 6;
  const int tid = threadIdx.x;
  const int lane = tid & 63, w = tid >> 6;
  const int lr = lane & 15, lg = lane >> 4;
  const int wm = w >> 1, wn = w & 1;

  f32x4 acc[4][2];
#pragma unroll
  for (int mr = 0; mr < 4; ++mr)
#pragma unroll
    for (int nr = 0; nr < 2; ++nr) acc[mr][nr] = (f32x4){0.f, 0.f, 0.f, 0.f};

  for (int k0 = 0; k0 < 192; k0 += 64) {
    {
      const int r = tid >> 1, c0 = (tid & 1) * 32;
      const unsigned short* src = A + (size_t)(row0 + r) * 192 + k0 + c0;
#pragma unroll
      for (int u = 0; u < 4; ++u)
        *(u16x8*)&As[r][c0 + u * 8] = *(const u16x8*)&src[u * 8];
    }
    {
      const int n = tid >> 2, c0 = (tid & 3) * 16;
      const unsigned short* src = Bt + (size_t)(col0 + n) * 192 + k0 + c0;
#pragma unroll
      for (int u = 0; u < 2; ++u)
        *(u16x8*)&Bs[n][c0 + u * 8] = *(const u16x8*)&src[u * 8];
    }
    __syncthreads();
#pragma unroll
    for (int ks = 0; ks < 2; ++ks) {
      bf16x8 a[4], b[2];
#pragma unroll
      for (int mr = 0; mr < 4; ++mr)
        a[mr] = *(const bf16x8*)&As[wm * 64 + mr * 16 + lr][ks * 32 + lg * 8];
#pragma unroll
      for (int nr = 0; nr < 2; ++nr)
        b[nr] = *(const bf16x8*)&Bs[wn * 32 + nr * 16 + lr][ks * 32 + lg * 8];
#pragma unroll
      for (int mr = 0; mr < 4; ++mr)
#pragma unroll
        for (int nr = 0; nr < 2; ++nr)
          acc[mr][nr] = __builtin_amdgcn_mfma_f32_16x16x32_bf16(a[mr], b[nr], acc[mr][nr], 0, 0, 0);
    }
    __syncthreads();
  }

#pragma unroll
  for (int mr = 0; mr < 4; ++mr) {
#pragma unroll
    for (int nr = 0; nr < 2; ++nr) {
      const int c = col0 + wn * 32 + nr * 16 + lr;
      const int rbase = row0 + wm * 64 + mr * 16 + lg * 4;
      if (isQ) {
        const int h = c >> 6, d = c & 63;
        const int b = rbase / 3136;
        const int n0 = rbase - b * 3136;
#pragma unroll
        for (int j = 0; j < 4; ++j)
          Qbuf[(((size_t)b * 3 + h) * 3136 + n0 + j) * 64 + d] = f2b(acc[mr][nr][j] * QSCALE);
      } else if (c < 192) {
        const int h = c >> 6, d = c & 63;
        const int b = rbase / 784;
        const int n0 = rbase - b * 784;
#pragma unroll
        for (int j = 0; j < 4; ++j)
          Kbuf[(((size_t)b * 3 + h) * 784 + n0 + j) * 64 + d] = f2b(acc[mr][nr][j]);
      } else {
        const int h = (c - 192) >> 6, d = (c - 192) & 63;
        const int b = rbase / 784;
        const int n0 = rbase - b * 784;
        uint2 v = pack4(acc[mr][nr][0], acc[mr][nr][1], acc[mr][nr][2], acc[mr][nr][3]);
        *reinterpret_cast<uint2*>(&Vtbuf[(((size_t)b * 3 + h) * 64 + d) * 784 + n0]) = v;
      }
    }
  }
}

// ---------------------------------------------------------------------------
// output projection (round-6 proven): O[25088,192](bf16) x Wo^T + bias -> fp32
// ---------------------------------------------------------------------------
__global__ __launch_bounds__(256) void gemm_out_kernel(
    const unsigned short* __restrict__ A, const unsigned short* __restrict__ Bt,
    const float* __restrict__ bias, float* __restrict__ O32)
{
  __shared__ unsigned short As[128][72];
  __shared__ unsigned short Bs[64][72];

  const int bm = blockIdx.x / 3, bn = blockIdx.x % 3;
  const int row0 = bm << 7, col0 = bn << 6;
  const int tid = threadIdx.x;
  const int lane = tid & 63, w = tid >> 6;
  const int lr = lane & 15, lg = lane >> 4;
  const int wm = w >> 1, wn = w & 1;

  f32x4 acc[4][2];
#pragma unroll
  for (int mr = 0; mr < 4; ++mr)
#pragma unroll
    for (int nr = 0; nr < 2; ++nr) acc[mr][nr] = (f32x4){0.f, 0.f, 0.f, 0.f};

  for (int k0 = 0; k0 < 192; k0 += 64) {
    {
      const int r = tid >> 1, c0 = (tid & 1) * 32;
      const unsigned short* src = A + (size_t)(row0 + r) * 192 + k0 + c0;
#pragma unroll
      for (int u = 0; u < 4; ++u)
        *(u16x8*)&As[r][c0 + u * 8] = *(const u16x8*)&src[u * 8];
    }
    {
      const int n = tid >> 2, c0 = (tid & 3) * 16;
      const unsigned short* src = Bt + (size_t)(col0 + n) * 192 + k0 + c0;
#pragma unroll
      for (int u = 0; u < 2; ++u)
        *(u16x8*)&Bs[n][c0 + u * 8] = *(const u16x8*)&src[u * 8];
    }
    __syncthreads();
#pragma unroll
    for (int ks = 0; ks < 2; ++ks) {
      bf16x8 a[4], b[2];
#pragma unroll
      for (int mr = 0; mr < 4; ++mr)
        a[mr] = *(const bf16x8*)&As[wm * 64 + mr * 16 + lr][ks * 32 + lg * 8];
#pragma unroll
      for (int nr = 0; nr < 2; ++nr)
        b[nr] = *(const bf16x8*)&Bs[wn * 32 + nr * 16 + lr][ks * 32 + lg * 8];
#pragma unroll
      for (int mr = 0; mr < 4; ++mr)
#pragma unroll
        for (int nr = 0; nr < 2; ++nr)
          acc[mr][nr] = __builtin_amdgcn_mfma_f32_16x16x32_bf16(a[mr], b[nr], acc[mr][nr], 0, 0, 0);
    }
    __syncthreads();
  }

#pragma unroll
  for (int mr = 0; mr < 4; ++mr) {
#pragma unroll
    for (int nr = 0; nr < 2; ++nr) {
      const int c = col0 + wn * 32 + nr * 16 + lr;
      const int rbase = row0 + wm * 64 + mr * 16 + lg * 4;
      const float bb = bias[c];
#pragma unroll
      for (int j = 0; j < 4; ++j)
        O32[(size_t)(rbase + j) * 192 + c] = acc[mr][nr][j] + bb;
    }
  }
}

// ---------------------------------------------------------------------------
// MFMA flash attention (round-11 structure: LDS-staged K/V + reg prefetch +
// XCD swizzle + setprio) with ZERO-LDS P: swapped-QK^T output st[nb] is
// bit-for-bit the A-fragment of v_mfma_f32_16x16x16_bf16 (row=lane&15,
// k=(lane>>4)*4+j), so P converts in-register (proven pack4) and PV runs as
// 16x16x16 MFMAs with 8-byte V B-frag LDS reads. Ps buffer deleted.
// ---------------------------------------------------------------------------
__global__ __launch_bounds__(256) void attn_mfma_kernel(
    const unsigned short* __restrict__ Qb, const unsigned short* __restrict__ Kb,
    const unsigned short* __restrict__ Vtb, unsigned short* __restrict__ Ob)
{
  __shared__ unsigned short Ks[64][72];
  __shared__ unsigned short Vts[64][72];   // V transposed tile: [d][kv_local]
  __shared__ float ls[4][16];

  const int raw = blockIdx.x;
  const int blk = (raw & 7) * 147 + (raw >> 3);  // XCD-chunked swizzle (8*147=1176)
  const int qt = blk % 49;
  const int bh = blk / 49;                 // b*3 + h
  const int n0 = qt * 64;
  const int tid = threadIdx.x;
  const int lane = tid & 63;
  const int w = tid >> 6;
  const int lr = lane & 15, lg = lane >> 4;
  const int srow = w * 16 + lr;            // staging row
  const int scc  = lg;                     // staging chunk

  const unsigned short* qrow = Qb + ((size_t)bh * NQ + n0 + w * 16 + lr) * 64;
  const bf16x8 aq0 = *(const bf16x8*)&qrow[lg * 8];
  const bf16x8 aq1 = *(const bf16x8*)&qrow[32 + lg * 8];

  const unsigned short* kbase = Kb + (size_t)bh * NKV * 64;
  const unsigned short* vrow  = Vtb + ((size_t)bh * 64 + srow) * NKV;

  u16x8 kr0, kr1, vr0, vr1;
  {
    const unsigned short* kp = kbase + (size_t)srow * 64;
    kr0 = *(const u16x8*)&kp[scc * 8];
    kr1 = *(const u16x8*)&kp[scc * 8 + 32];
    vr0 = *(const u16x8*)&vrow[scc * 8];
    vr1 = *(const u16x8*)&vrow[scc * 8 + 32];
  }
  *(u16x8*)&Ks[srow][scc * 8]       = kr0;
  *(u16x8*)&Ks[srow][scc * 8 + 32]  = kr1;
  *(u16x8*)&Vts[srow][scc * 8]      = vr0;
  *(u16x8*)&Vts[srow][scc * 8 + 32] = vr1;
  __syncthreads();

  f32x4 oacc[4];
#pragma unroll
  for (int db = 0; db < 4; ++db) oacc[db] = (f32x4){0.f, 0.f, 0.f, 0.f};
  float lsum = 0.f;

  for (int kt = 0; kt < 12; ++kt) {
    // prefetch tile kt+1 into regs (latency hides under compute)
    {
      const int nk = kt + 1;
      const int kvg = (nk * 64 + srow < NKV) ? nk * 64 + srow : NKV - 1;
      const unsigned short* kp = kbase + (size_t)kvg * 64;
      kr0 = *(const u16x8*)&kp[scc * 8];
      kr1 = *(const u16x8*)&kp[scc * 8 + 32];
      const int vb = nk * 64 + scc * 8;
      const int vc0 = (vb      <= NKV - 8) ? vb      : NKV - 8;
      const int vc1 = (vb + 32 <= NKV - 8) ? vb + 32 : NKV - 8;
      vr0 = *(const u16x8*)&vrow[vc0];
      vr1 = *(const u16x8*)&vrow[vc1];
    }

    // S^T = K.Q^T : st[nb][r] = S[q=lr][kv = kt*64 + nb*16 + lg*4 + r]
    f32x4 st[4];
    __builtin_amdgcn_s_setprio(1);
#pragma unroll
    for (int nb = 0; nb < 4; ++nb) {
      const bf16x8 bk0 = *(const bf16x8*)&Ks[nb * 16 + lr][lg * 8];
      const bf16x8 bk1 = *(const bf16x8*)&Ks[nb * 16 + lr][32 + lg * 8];
      f32x4 a = (f32x4){0.f, 0.f, 0.f, 0.f};
      a = __builtin_amdgcn_mfma_f32_16x16x32_bf16(bk0, aq0, a, 0, 0, 0);
      a = __builtin_amdgcn_mfma_f32_16x16x32_bf16(bk1, aq1, a, 0, 0, 0);
      st[nb] = a;
    }
    __builtin_amdgcn_s_setprio(0);

    // p = exp2(s') -> bf16x4 A-frags ENTIRELY IN REGISTERS (no LDS P)
    bf16x4 pa[4];
#pragma unroll
    for (int nb = 0; nb < 4; ++nb) {
      float p[4];
#pragma unroll
      for (int r = 0; r < 4; ++r) p[r] = exp2f(st[nb][r]);
      lsum += (p[0] + p[1]) + (p[2] + p[3]);
      uint2 u = pack4(p[0], p[1], p[2], p[3]);
      pa[nb] = __builtin_bit_cast(bf16x4, u);
    }

    // O += P V : 16x16x16 MFMA; A-frag = pa[nb] (k = lg*4+j over kv slice
    // nb*16), B-frag = Vts[d=db*16+lr][nb*16 + lg*4 .. +4]
    __builtin_amdgcn_s_setprio(1);
#pragma unroll
    for (int db = 0; db < 4; ++db) {
#pragma unroll
      for (int nb = 0; nb < 4; ++nb) {
        const bf16x4 vb = *(const bf16x4*)&Vts[db * 16 + lr][nb * 16 + lg * 4];
        oacc[db] = __builtin_amdgcn_mfma_f32_16x16x16bf16_1k(pa[nb], vb, oacc[db], 0, 0, 0);
      }
    }
    __builtin_amdgcn_s_setprio(0);

    // publish prefetched tile kt+1
    __syncthreads();
    *(u16x8*)&Ks[srow][scc * 8]       = kr0;
    *(u16x8*)&Ks[srow][scc * 8 + 32]  = kr1;
    *(u16x8*)&Vts[srow][scc * 8]      = vr0;
    *(u16x8*)&Vts[srow][scc * 8 + 32] = vr1;
    __syncthreads();
  }

  // tail tile (kt=12): kv 768..783 valid -> only nb=0 slice (exactly 16 kv)
  {
    const bf16x8 bk0 = *(const bf16x8*)&Ks[lr][lg * 8];
    const bf16x8 bk1 = *(const bf16x8*)&Ks[lr][32 + lg * 8];
    f32x4 a = (f32x4){0.f, 0.f, 0.f, 0.f};
    a = __builtin_amdgcn_mfma_f32_16x16x32_bf16(bk0, aq0, a, 0, 0, 0);
    a = __builtin_amdgcn_mfma_f32_16x16x32_bf16(bk1, aq1, a, 0, 0, 0);
    float p[4];
#pragma unroll
    for (int r = 0; r < 4; ++r) p[r] = exp2f(a[r]);   // lg*4+r < 16: all valid
    lsum += (p[0] + p[1]) + (p[2] + p[3]);
    uint2 u = pack4(p[0], p[1], p[2], p[3]);
    const bf16x4 pa0 = __builtin_bit_cast(bf16x4, u);
#pragma unroll
    for (int db = 0; db < 4; ++db) {
      const bf16x4 vb = *(const bf16x4*)&Vts[db * 16 + lr][lg * 4];
      oacc[db] = __builtin_amdgcn_mfma_f32_16x16x16bf16_1k(pa0, vb, oacc[db], 0, 0, 0);
    }
  }

  // final denominator: lanes {lr, lr+16, lr+32, lr+48} hold partials for q=lr
  float l = lsum;
  l += __shfl_xor(l, 16);
  l += __shfl_xor(l, 32);
  if (lg == 0) ls[w][lr] = l;
  const float4 lv = *(const float4*)&ls[w][lg * 4];   // wave-private, in-order

  const int b = bh / 3, h = bh - b * 3;
  float linv[4];
#pragma unroll
  for (int j = 0; j < 4; ++j) linv[j] = 1.f / ((&lv.x)[j]);
#pragma unroll
  for (int j = 0; j < 4; ++j) {
    const int qg = n0 + w * 16 + lg * 4 + j;
    unsigned short* orow = Ob + ((size_t)b * NQ + qg) * 192 + h * 64 + lr;
#pragma unroll
    for (int db = 0; db < 4; ++db) orow[db * 16] = f2b(oacc[db][j] * linv[j]);
  }
}

// ---------------------------------------------------------------------------
extern "C" void kernel_launch(void* const* d_in, const int* in_sizes, int n_in,
                              void* d_out, int out_size, void* d_ws, size_t ws_size,
                              hipStream_t stream)
{
  const float* x        = (const float*)d_in[0];
  const float* dw_q     = (const float*)d_in[1];
  const float* q_gamma  = (const float*)d_in[2];
  const float* q_beta   = (const float*)d_in[3];
  const float* q_mean   = (const float*)d_in[4];
  const float* q_var    = (const float*)d_in[5];
  const float* pw_q     = (const float*)d_in[6];
  const float* dw_kv    = (const float*)d_in[7];
  const float* kv_gamma = (const float*)d_in[8];
  const float* kv_beta  = (const float*)d_in[9];
  const float* kv_mean  = (const float*)d_in[10];
  const float* kv_var   = (const float*)d_in[11];
  const float* pw_kv    = (const float*)d_in[12];
  const float* out_w    = (const float*)d_in[13];
  const float* out_b    = (const float*)d_in[14];
  float* out = (float*)d_out;

  unsigned short* dwq   = (unsigned short*)d_ws;          // 25088*192 (later O)
  unsigned short* dwkv  = dwq   + (size_t)25088 * 192;    // 6272*192
  unsigned short* Qbuf  = dwkv  + (size_t)6272 * 192;     // 24*3136*64
  unsigned short* Kbuf  = Qbuf  + (size_t)24 * 3136 * 64; // 24*784*64
  unsigned short* Vtbuf = Kbuf  + (size_t)24 * 784 * 64;  // 24*64*784
  unsigned short* Wq    = Vtbuf + (size_t)24 * 784 * 64;  // 192*192
  unsigned short* Wkv   = Wq + 36864;                     // 384*192
  unsigned short* Wo    = Wkv + 73728;                    // 192*192

  // 1. fused: dwbn(q) + dwbn(kv) + weight prep
  stage1_kernel<<<6456, 256, 0, stream>>>(
      x, dw_q, q_gamma, q_beta, q_mean, q_var,
      dw_kv, kv_gamma, kv_beta, kv_mean, kv_var,
      pw_q, pw_kv, out_w, dwq, dwkv, Wq, Wkv, Wo);
  // 2. pointwise GEMMs (round-6 tiling): q -> Qbuf, kv -> Kbuf + Vtbuf
  gemm_qkv_kernel<<<882, 256, 0, stream>>>(dwq, dwkv, Wq, Wkv, Qbuf, Kbuf, Vtbuf);
  // 3. MFMA attention (zero-LDS P, 16x16x16 PV) -> dwq
  attn_mfma_kernel<<<8 * 3 * 49, 256, 0, stream>>>(Qbuf, Kbuf, Vtbuf, dwq);
  // 4. output projection + bias -> d_out (fp32)
  gemm_out_kernel<<<588, 256, 0, stream>>>(dwq, Wo, out_b, out);
}

// Round 14
// 90.284 us; speedup vs baseline: 1.4590x; 1.0301x over previous
//
#include <hip/hip_runtime.h>
#include <hip/hip_bf16.h>

namespace {
constexpr int Bb = 8, Hh = 56, Ww = 56, Cc = 192;
constexpr int NQ  = Hh * Ww;        // 3136
constexpr int NKV = 28 * 28;        // 784
constexpr float EPS = 1e-5f;
constexpr float QSCALE = 0.125f * 1.4426950408889634f;  // head scale * log2(e)
}

typedef __attribute__((ext_vector_type(8))) short          bf16x8;
typedef __attribute__((ext_vector_type(4))) float          f32x4;
typedef __attribute__((ext_vector_type(8))) unsigned short u16x8;

__device__ inline unsigned short f2b(float f) {
  __hip_bfloat16 h = __float2bfloat16(f);     // RNE, hardware cvt path
  return __builtin_bit_cast(unsigned short, h);
}

__device__ inline uint2 pack4(float a, float b, float c, float d) {
  uint2 r;
  r.x = (unsigned)f2b(a) | ((unsigned)f2b(b) << 16);
  r.y = (unsigned)f2b(c) | ((unsigned)f2b(d) << 16);
  return r;
}

// ---------------------------------------------------------------------------
// depthwise 3x3 conv (SAME) + batchnorm body (4 channels / thread)
// ---------------------------------------------------------------------------
__device__ inline void dwbn_body(
    int idx, const float* __restrict__ x, const float* __restrict__ w,
    const float* __restrict__ gamma, const float* __restrict__ beta,
    const float* __restrict__ mean, const float* __restrict__ var,
    unsigned short* __restrict__ out, int OH, int OW, int stride, int pad)
{
  int c4 = idx % 48;
  int t = idx / 48;
  int ow = t % OW; t /= OW;
  int oh = t % OH; int b = t / OH;
  const int c = c4 * 4;

  float4 acc = make_float4(0.f, 0.f, 0.f, 0.f);
#pragma unroll
  for (int kh = 0; kh < 3; ++kh) {
    int ih = oh * stride - pad + kh;
    if (ih < 0 || ih >= Hh) continue;
#pragma unroll
    for (int kw = 0; kw < 3; ++kw) {
      int iw = ow * stride - pad + kw;
      if (iw < 0 || iw >= Ww) continue;
      float4 xv = *(const float4*)&x[((size_t)(b * Hh + ih) * Ww + iw) * Cc + c];
      float4 wv = *(const float4*)&w[(kh * 3 + kw) * Cc + c];
      acc.x += xv.x * wv.x; acc.y += xv.y * wv.y;
      acc.z += xv.z * wv.z; acc.w += xv.w * wv.w;
    }
  }
  float4 gm = *(const float4*)&gamma[c];
  float4 bt = *(const float4*)&beta[c];
  float4 mn = *(const float4*)&mean[c];
  float4 vr = *(const float4*)&var[c];
  float r0 = (acc.x - mn.x) * gm.x / sqrtf(vr.x + EPS) + bt.x;
  float r1 = (acc.y - mn.y) * gm.y / sqrtf(vr.y + EPS) + bt.y;
  float r2 = (acc.z - mn.z) * gm.z / sqrtf(vr.z + EPS) + bt.z;
  float r3 = (acc.w - mn.w) * gm.w / sqrtf(vr.w + EPS) + bt.w;
  const size_t row = (size_t)(b * OH + oh) * OW + ow;
  *reinterpret_cast<uint2*>(&out[row * 192 + c]) = pack4(r0, r1, r2, r3);
}

// ---------------------------------------------------------------------------
// fused stage 1: dwbn(q) [blocks 0..4703] + dwbn(kv) [4704..5879]
//              + weight transpose->bf16 [5880..6455]
// ---------------------------------------------------------------------------
__global__ __launch_bounds__(256) void stage1_kernel(
    const float* __restrict__ x,
    const float* __restrict__ dw_q, const float* __restrict__ q_gamma,
    const float* __restrict__ q_beta, const float* __restrict__ q_mean,
    const float* __restrict__ q_var,
    const float* __restrict__ dw_kv, const float* __restrict__ kv_gamma,
    const float* __restrict__ kv_beta, const float* __restrict__ kv_mean,
    const float* __restrict__ kv_var,
    const float* __restrict__ pwq, const float* __restrict__ pwkv,
    const float* __restrict__ outw,
    unsigned short* __restrict__ dwq, unsigned short* __restrict__ dwkv,
    unsigned short* __restrict__ wq, unsigned short* __restrict__ wkv,
    unsigned short* __restrict__ wo)
{
  const int blk = blockIdx.x;
  if (blk < 4704) {
    dwbn_body(blk * 256 + threadIdx.x, x, dw_q, q_gamma, q_beta, q_mean, q_var,
              dwq, 56, 56, 1, 1);
  } else if (blk < 5880) {
    dwbn_body((blk - 4704) * 256 + threadIdx.x, x, dw_kv, kv_gamma, kv_beta,
              kv_mean, kv_var, dwkv, 28, 28, 2, 0);
  } else {
    int i = (blk - 5880) * 256 + threadIdx.x;
    if (i < 36864) {                       // wq [192][192]
      int n = i / 192, k = i - n * 192;
      wq[i] = f2b(pwq[k * 192 + n]);
    } else if (i < 110592) {               // wkv [384][192]
      int j = i - 36864;
      int n = j / 192, k = j - n * 192;
      wkv[j] = f2b(pwkv[k * 384 + n]);
    } else {                               // wo [192][192]
      int j = i - 110592;
      int n = j / 192, k = j - n * 192;
      wo[j] = f2b(outw[k * 192 + n]);
    }
  }
}

// ---------------------------------------------------------------------------
// bf16 MFMA GEMM for q & kv pointwise (round-6 proven 128x64 tiling) with
// XCD-chunked bijective block swizzle (m204; nwg=882, q=110, r=2): same-bm
// col-blocks (sharing an A panel) stay on one XCD's L2.
// ---------------------------------------------------------------------------
__global__ __launch_bounds__(256) void gemm_qkv_kernel(
    const unsigned short* __restrict__ dwq, const unsigned short* __restrict__ dwkv,
    const unsigned short* __restrict__ Wq, const unsigned short* __restrict__ Wkv,
    unsigned short* __restrict__ Qbuf, unsigned short* __restrict__ Kbuf,
    unsigned short* __restrict__ Vtbuf)
{
  __shared__ unsigned short As[128][72];
  __shared__ unsigned short Bs[64][72];

  const int raw = blockIdx.x;
  const int x8 = raw & 7, ci = raw >> 3;         // 882 = 2*111 + 6*110
  const int blk = (x8 < 2 ? x8 * 111 : 222 + (x8 - 2) * 110) + ci;
  const bool isQ = blk < 588;
  const int lb = isQ ? blk : blk - 588;
  const unsigned short* __restrict__ A  = isQ ? dwq : dwkv;
  const unsigned short* __restrict__ Bt = isQ ? Wq : Wkv;
  const int nbl = isQ ? 3 : 6;
  const int NR  = isQ ? 3136 : 784;

  const int bm = lb / nbl, bn = lb % nbl;
  const int row0 = bm << 7, col0 = bn << 6;
  const int tid = threadIdx.x;
  const int lane = tid & 63, w = tid >> 6;
  const int lr = lane & 15, lg = lane >> 4;
  const int wm = w >> 1, wn = w & 1;

  f32x4 acc[4][2];
#pragma unroll
  for (int mr = 0; mr < 4; ++mr)
#pragma unroll
    for (int nr = 0; nr < 2; ++nr) acc[mr][nr] = (f32x4){0.f, 0.f, 0.f, 0.f};

  for (int k0 = 0; k0 < 192; k0 += 64) {
    {
      const int r = tid >> 1, c0 = (tid & 1) * 32;
      const unsigned short* src = A + (size_t)(row0 + r) * 192 + k0 + c0;
#pragma unroll
      for (int u = 0; u < 4; ++u)
        *(u16x8*)&As[r][c0 + u * 8] = *(const u16x8*)&src[u * 8];
    }
    {
      const int n = tid >> 2, c0 = (tid & 3) * 16;
      const unsigned short* src = Bt + (size_t)(col0 + n) * 192 + k0 + c0;
#pragma unroll
      for (int u = 0; u < 2; ++u)
        *(u16x8*)&Bs[n][c0 + u * 8] = *(const u16x8*)&src[u * 8];
    }
    __syncthreads();
#pragma unroll
    for (int ks = 0; ks < 2; ++ks) {
      bf16x8 a[4], b[2];
#pragma unroll
      for (int mr = 0; mr < 4; ++mr)
        a[mr] = *(const bf16x8*)&As[wm * 64 + mr * 16 + lr][ks * 32 + lg * 8];
#pragma unroll
      for (int nr = 0; nr < 2; ++nr)
        b[nr] = *(const bf16x8*)&Bs[wn * 32 + nr * 16 + lr][ks * 32 + lg * 8];
#pragma unroll
      for (int mr = 0; mr < 4; ++mr)
#pragma unroll
        for (int nr = 0; nr < 2; ++nr)
          acc[mr][nr] = __builtin_amdgcn_mfma_f32_16x16x32_bf16(a[mr], b[nr], acc[mr][nr], 0, 0, 0);
    }
    __syncthreads();
  }

#pragma unroll
  for (int mr = 0; mr < 4; ++mr) {
#pragma unroll
    for (int nr = 0; nr < 2; ++nr) {
      const int c = col0 + wn * 32 + nr * 16 + lr;
      const int rbase = row0 + wm * 64 + mr * 16 + lg * 4;
      if (isQ) {
        const int h = c >> 6, d = c & 63;
        const int b = rbase / 3136;
        const int n0 = rbase - b * 3136;
#pragma unroll
        for (int j = 0; j < 4; ++j)
          Qbuf[(((size_t)b * 3 + h) * 3136 + n0 + j) * 64 + d] = f2b(acc[mr][nr][j] * QSCALE);
      } else if (c < 192) {
        const int h = c >> 6, d = c & 63;
        const int b = rbase / 784;
        const int n0 = rbase - b * 784;
#pragma unroll
        for (int j = 0; j < 4; ++j)
          Kbuf[(((size_t)b * 3 + h) * 784 + n0 + j) * 64 + d] = f2b(acc[mr][nr][j]);
      } else {
        const int h = (c - 192) >> 6, d = (c - 192) & 63;
        const int b = rbase / 784;
        const int n0 = rbase - b * 784;
        uint2 v = pack4(acc[mr][nr][0], acc[mr][nr][1], acc[mr][nr][2], acc[mr][nr][3]);
        *reinterpret_cast<uint2*>(&Vtbuf[(((size_t)b * 3 + h) * 64 + d) * 784 + n0]) = v;
      }
    }
  }
}

// ---------------------------------------------------------------------------
// output projection (round-6 proven) + XCD-chunked swizzle (nwg=588, q=73,
// r=4): same-bm col-blocks share one XCD's L2 for the A panel.
// ---------------------------------------------------------------------------
__global__ __launch_bounds__(256) void gemm_out_kernel(
    const unsigned short* __restrict__ A, const unsigned short* __restrict__ Bt,
    const float* __restrict__ bias, float* __restrict__ O32)
{
  __shared__ unsigned short As[128][72];
  __shared__ unsigned short Bs[64][72];

  const int raw = blockIdx.x;
  const int x8 = raw & 7, ci = raw >> 3;         // 588 = 4*74 + 4*73
  const int blk = (x8 < 4 ? x8 * 74 : 296 + (x8 - 4) * 73) + ci;
  const int bm = blk / 3, bn = blk % 3;
  const int row0 = bm << 7, col0 = bn << 6;
  const int tid = threadIdx.x;
  const int lane = tid & 63, w = tid >> 6;
  const int lr = lane & 15, lg = lane >> 4;
  const int wm = w >> 1, wn = w & 1;

  f32x4 acc[4][2];
#pragma unroll
  for (int mr = 0; mr < 4; ++mr)
#pragma unroll
    for (int nr = 0; nr < 2; ++nr) acc[mr][nr] = (f32x4){0.f, 0.f, 0.f, 0.f};

  for (int k0 = 0; k0 < 192; k0 += 64) {
    {
      const int r = tid >> 1, c0 = (tid & 1) * 32;
      const unsigned short* src = A + (size_t)(row0 + r) * 192 + k0 + c0;
#pragma unroll
      for (int u = 0; u < 4; ++u)
        *(u16x8*)&As[r][c0 + u * 8] = *(const u16x8*)&src[u * 8];
    }
    {
      const int n = tid >> 2, c0 = (tid & 3) * 16;
      const unsigned short* src = Bt + (size_t)(col0 + n) * 192 + k0 + c0;
#pragma unroll
      for (int u = 0; u < 2; ++u)
        *(u16x8*)&Bs[n][c0 + u * 8] = *(const u16x8*)&src[u * 8];
    }
    __syncthreads();
#pragma unroll
    for (int ks = 0; ks < 2; ++ks) {
      bf16x8 a[4], b[2];
#pragma unroll
      for (int mr = 0; mr < 4; ++mr)
        a[mr] = *(const bf16x8*)&As[wm * 64 + mr * 16 + lr][ks * 32 + lg * 8];
#pragma unroll
      for (int nr = 0; nr < 2; ++nr)
        b[nr] = *(const bf16x8*)&Bs[wn * 32 + nr * 16 + lr][ks * 32 + lg * 8];
#pragma unroll
      for (int mr = 0; mr < 4; ++mr)
#pragma unroll
        for (int nr = 0; nr < 2; ++nr)
          acc[mr][nr] = __builtin_amdgcn_mfma_f32_16x16x32_bf16(a[mr], b[nr], acc[mr][nr], 0, 0, 0);
    }
    __syncthreads();
  }

#pragma unroll
  for (int mr = 0; mr < 4; ++mr) {
#pragma unroll
    for (int nr = 0; nr < 2; ++nr) {
      const int c = col0 + wn * 32 + nr * 16 + lr;
      const int rbase = row0 + wm * 64 + mr * 16 + lg * 4;
      const float bb = bias[c];
#pragma unroll
      for (int j = 0; j < 4; ++j)
        O32[(size_t)(rbase + j) * 192 + c] = acc[mr][nr][j] + bb;
    }
  }
}

// ---------------------------------------------------------------------------
// MFMA flash attention: round-11 proven structure (LDS-staged K/V + reg
// prefetch + XCD swizzle + setprio + b128 LDS-P PV) with SINGLE-BARRIER
// double-buffered K/V: writes go to buf[cur^1], reads from buf[cur]; the
// previous iteration's barrier orders writes vs the reads-of-two-ago.
// Barriers per block: 26 -> 13. Per-row arithmetic identical to round 6.
// ---------------------------------------------------------------------------
__global__ __launch_bounds__(256) void attn_mfma_kernel(
    const unsigned short* __restrict__ Qb, const unsigned short* __restrict__ Kb,
    const unsigned short* __restrict__ Vtb, unsigned short* __restrict__ Ob)
{
  __shared__ unsigned short Ks[2][64][72];
  __shared__ unsigned short Vts[2][64][72];  // V transposed tile: [d][kv_local]
  __shared__ unsigned short Ps[64][72];      // P tile (wave-private rows)
  __shared__ float ls[4][16];

  const int raw = blockIdx.x;
  const int blk = (raw & 7) * 147 + (raw >> 3);  // XCD-chunked swizzle (8*147=1176)
  const int qt = blk % 49;
  const int bh = blk / 49;                 // b*3 + h
  const int n0 = qt * 64;
  const int tid = threadIdx.x;
  const int lane = tid & 63;
  const int w = tid >> 6;
  const int lr = lane & 15, lg = lane >> 4;
  const int srow = w * 16 + lr;            // staging row
  const int scc  = lg;                     // staging chunk

  const unsigned short* qrow = Qb + ((size_t)bh * NQ + n0 + w * 16 + lr) * 64;
  const bf16x8 aq0 = *(const bf16x8*)&qrow[lg * 8];
  const bf16x8 aq1 = *(const bf16x8*)&qrow[32 + lg * 8];

  const unsigned short* kbase = Kb + (size_t)bh * NKV * 64;
  const unsigned short* vrow  = Vtb + ((size_t)bh * 64 + srow) * NKV;

  // stage tile 0 -> buffer 0
  u16x8 kr0, kr1, vr0, vr1;
  {
    const unsigned short* kp = kbase + (size_t)srow * 64;
    kr0 = *(const u16x8*)&kp[scc * 8];
    kr1 = *(const u16x8*)&kp[scc * 8 + 32];
    vr0 = *(const u16x8*)&vrow[scc * 8];
    vr1 = *(const u16x8*)&vrow[scc * 8 + 32];
  }
  *(u16x8*)&Ks[0][srow][scc * 8]       = kr0;
  *(u16x8*)&Ks[0][srow][scc * 8 + 32]  = kr1;
  *(u16x8*)&Vts[0][srow][scc * 8]      = vr0;
  *(u16x8*)&Vts[0][srow][scc * 8 + 32] = vr1;
  __syncthreads();

  f32x4 oacc[4];
#pragma unroll
  for (int db = 0; db < 4; ++db) oacc[db] = (f32x4){0.f, 0.f, 0.f, 0.f};
  float lsum = 0.f;

  int cur = 0;
  for (int kt = 0; kt < 12; ++kt) {
    // prefetch tile kt+1 into regs (latency hides under compute)
    {
      const int nk = kt + 1;
      const int kvg = (nk * 64 + srow < NKV) ? nk * 64 + srow : NKV - 1;
      const unsigned short* kp = kbase + (size_t)kvg * 64;
      kr0 = *(const u16x8*)&kp[scc * 8];
      kr1 = *(const u16x8*)&kp[scc * 8 + 32];
      const int vb = nk * 64 + scc * 8;
      const int vc0 = (vb      <= NKV - 8) ? vb      : NKV - 8;
      const int vc1 = (vb + 32 <= NKV - 8) ? vb + 32 : NKV - 8;
      vr0 = *(const u16x8*)&vrow[vc0];
      vr1 = *(const u16x8*)&vrow[vc1];
    }

    // S^T = K.Q^T : st[nb][r] = S[q=lr][kv = kt*64 + nb*16 + lg*4 + r]
    f32x4 st[4];
    __builtin_amdgcn_s_setprio(1);
#pragma unroll
    for (int nb = 0; nb < 4; ++nb) {
      const bf16x8 bk0 = *(const bf16x8*)&Ks[cur][nb * 16 + lr][lg * 8];
      const bf16x8 bk1 = *(const bf16x8*)&Ks[cur][nb * 16 + lr][32 + lg * 8];
      f32x4 a = (f32x4){0.f, 0.f, 0.f, 0.f};
      a = __builtin_amdgcn_mfma_f32_16x16x32_bf16(bk0, aq0, a, 0, 0, 0);
      a = __builtin_amdgcn_mfma_f32_16x16x32_bf16(bk1, aq1, a, 0, 0, 0);
      st[nb] = a;
    }
    __builtin_amdgcn_s_setprio(0);

    // p = exp2(s') (log2e pre-folded into Q), partial denom, pack -> Ps
#pragma unroll
    for (int nb = 0; nb < 4; ++nb) {
      float p[4];
#pragma unroll
      for (int r = 0; r < 4; ++r) p[r] = exp2f(st[nb][r]);
      lsum += (p[0] + p[1]) + (p[2] + p[3]);
      uint2 u = pack4(p[0], p[1], p[2], p[3]);
      *reinterpret_cast<uint2*>(&Ps[w * 16 + lr][nb * 16 + lg * 4]) = u;
    }

    // O += P V  (Ps rows wave-private: same-wave DS in-order, no barrier)
    const bf16x8 pa0 = *(const bf16x8*)&Ps[w * 16 + lr][lg * 8];
    const bf16x8 pa1 = *(const bf16x8*)&Ps[w * 16 + lr][32 + lg * 8];
    __builtin_amdgcn_s_setprio(1);
#pragma unroll
    for (int db = 0; db < 4; ++db) {
      const bf16x8 vb0 = *(const bf16x8*)&Vts[cur][db * 16 + lr][lg * 8];
      const bf16x8 vb1 = *(const bf16x8*)&Vts[cur][db * 16 + lr][32 + lg * 8];
      oacc[db] = __builtin_amdgcn_mfma_f32_16x16x32_bf16(pa0, vb0, oacc[db], 0, 0, 0);
      oacc[db] = __builtin_amdgcn_mfma_f32_16x16x32_bf16(pa1, vb1, oacc[db], 0, 0, 0);
    }
    __builtin_amdgcn_s_setprio(0);

    // publish prefetched tile kt+1 into the OTHER buffer; one barrier
    *(u16x8*)&Ks[cur ^ 1][srow][scc * 8]       = kr0;
    *(u16x8*)&Ks[cur ^ 1][srow][scc * 8 + 32]  = kr1;
    *(u16x8*)&Vts[cur ^ 1][srow][scc * 8]      = vr0;
    *(u16x8*)&Vts[cur ^ 1][srow][scc * 8 + 32] = vr1;
    __syncthreads();
    cur ^= 1;
  }

  // tail tile (kt=12): kv 768..783 valid -> only nb=0; zero nb=1 slot
  {
    const bf16x8 bk0 = *(const bf16x8*)&Ks[cur][lr][lg * 8];
    const bf16x8 bk1 = *(const bf16x8*)&Ks[cur][lr][32 + lg * 8];
    f32x4 a = (f32x4){0.f, 0.f, 0.f, 0.f};
    a = __builtin_amdgcn_mfma_f32_16x16x32_bf16(bk0, aq0, a, 0, 0, 0);
    a = __builtin_amdgcn_mfma_f32_16x16x32_bf16(bk1, aq1, a, 0, 0, 0);
    float p[4];
#pragma unroll
    for (int r = 0; r < 4; ++r) p[r] = exp2f(a[r]);   // lg*4+r < 16: all valid
    lsum += (p[0] + p[1]) + (p[2] + p[3]);
    *reinterpret_cast<uint2*>(&Ps[w * 16 + lr][lg * 4]) = pack4(p[0], p[1], p[2], p[3]);
    uint2 z; z.x = 0u; z.y = 0u;
    *reinterpret_cast<uint2*>(&Ps[w * 16 + lr][16 + lg * 4]) = z;
    const bf16x8 pa0 = *(const bf16x8*)&Ps[w * 16 + lr][lg * 8];
#pragma unroll
    for (int db = 0; db < 4; ++db) {
      const bf16x8 vb0 = *(const bf16x8*)&Vts[cur][db * 16 + lr][lg * 8];
      oacc[db] = __builtin_amdgcn_mfma_f32_16x16x32_bf16(pa0, vb0, oacc[db], 0, 0, 0);
    }
  }

  // final denominator: lanes {lr, lr+16, lr+32, lr+48} hold partials for q=lr
  float l = lsum;
  l += __shfl_xor(l, 16);
  l += __shfl_xor(l, 32);
  if (lg == 0) ls[w][lr] = l;
  const float4 lv = *(const float4*)&ls[w][lg * 4];   // wave-private, in-order

  const int b = bh / 3, h = bh - b * 3;
  float linv[4];
#pragma unroll
  for (int j = 0; j < 4; ++j) linv[j] = 1.f / ((&lv.x)[j]);
#pragma unroll
  for (int j = 0; j < 4; ++j) {
    const int qg = n0 + w * 16 + lg * 4 + j;
    unsigned short* orow = Ob + ((size_t)b * NQ + qg) * 192 + h * 64 + lr;
#pragma unroll
    for (int db = 0; db < 4; ++db) orow[db * 16] = f2b(oacc[db][j] * linv[j]);
  }
}

// ---------------------------------------------------------------------------
extern "C" void kernel_launch(void* const* d_in, const int* in_sizes, int n_in,
                              void* d_out, int out_size, void* d_ws, size_t ws_size,
                              hipStream_t stream)
{
  const float* x        = (const float*)d_in[0];
  const float* dw_q     = (const float*)d_in[1];
  const float* q_gamma  = (const float*)d_in[2];
  const float* q_beta   = (const float*)d_in[3];
  const float* q_mean   = (const float*)d_in[4];
  const float* q_var    = (const float*)d_in[5];
  const float* pw_q     = (const float*)d_in[6];
  const float* dw_kv    = (const float*)d_in[7];
  const float* kv_gamma = (const float*)d_in[8];
  const float* kv_beta  = (const float*)d_in[9];
  const float* kv_mean  = (const float*)d_in[10];
  const float* kv_var   = (const float*)d_in[11];
  const float* pw_kv    = (const float*)d_in[12];
  const float* out_w    = (const float*)d_in[13];
  const float* out_b    = (const float*)d_in[14];
  float* out = (float*)d_out;

  unsigned short* dwq   = (unsigned short*)d_ws;          // 25088*192 (later O)
  unsigned short* dwkv  = dwq   + (size_t)25088 * 192;    // 6272*192
  unsigned short* Qbuf  = dwkv  + (size_t)6272 * 192;     // 24*3136*64
  unsigned short* Kbuf  = Qbuf  + (size_t)24 * 3136 * 64; // 24*784*64
  unsigned short* Vtbuf = Kbuf  + (size_t)24 * 784 * 64;  // 24*64*784
  unsigned short* Wq    = Vtbuf + (size_t)24 * 784 * 64;  // 192*192
  unsigned short* Wkv   = Wq + 36864;                     // 384*192
  unsigned short* Wo    = Wkv + 73728;                    // 192*192

  // 1. fused: dwbn(q) + dwbn(kv) + weight prep
  stage1_kernel<<<6456, 256, 0, stream>>>(
      x, dw_q, q_gamma, q_beta, q_mean, q_var,
      dw_kv, kv_gamma, kv_beta, kv_mean, kv_var,
      pw_q, pw_kv, out_w, dwq, dwkv, Wq, Wkv, Wo);
  // 2. pointwise GEMMs (round-6 tiling + XCD swizzle): q -> Qbuf, kv -> K/Vt
  gemm_qkv_kernel<<<882, 256, 0, stream>>>(dwq, dwkv, Wq, Wkv, Qbuf, Kbuf, Vtbuf);
  // 3. MFMA attention (single-barrier dbuf K/V) -> dwq
  attn_mfma_kernel<<<8 * 3 * 49, 256, 0, stream>>>(Qbuf, Kbuf, Vtbuf, dwq);
  // 4. output projection + bias (XCD swizzle) -> d_out (fp32)
  gemm_out_kernel<<<588, 256, 0, stream>>>(dwq, Wo, out_b, out);
}